// Round 1
// baseline (254.725 us; speedup 1.0000x reference)
//
#include <hip/hip_runtime.h>

// BilinearSampler: img [B,H,W,C] f32, x_s/y_s [B,H,W] f32 in [-1,1] -> out [B,H,W,C] f32
// B=16, H=256, W=256, C=32.
// Mapping: 8 threads per pixel, each thread handles one float4 channel group.
// Wave of 64 lanes = 8 consecutive pixels * full C -> 1 KiB contiguous store.

constexpr int Bn = 16;
constexpr int Hn = 256;
constexpr int Wn = 256;
constexpr int Cn = 32;
constexpr int CG = Cn / 4;  // 8 float4 groups per pixel

__global__ __launch_bounds__(256) void bilinear_kernel(
    const float* __restrict__ img,
    const float* __restrict__ xs,
    const float* __restrict__ ys,
    float* __restrict__ out)
{
    const int t   = blockIdx.x * blockDim.x + threadIdx.x;
    const int pix = t >> 3;        // pixel index over B*H*W (grid sized exactly)
    const int cg  = t & 7;         // channel group (float4 index)

    const float xsv = xs[pix];
    const float ysv = ys[pix];

    const float x = 0.5f * (xsv + 1.0f) * (float)(Wn - 1);
    const float y = 0.5f * (ysv + 1.0f) * (float)(Hn - 1);

    const float xf = floorf(x);
    const float yf = floorf(y);
    int x0 = (int)xf;
    int y0 = (int)yf;
    int x1 = x0 + 1;
    int y1 = y0 + 1;

    const int x0c = min(max(x0, 0), Wn - 1);
    const int x1c = min(max(x1, 0), Wn - 1);
    const int y0c = min(max(y0, 0), Hn - 1);
    const int y1c = min(max(y1, 0), Hn - 1);

    // weights from CLAMPED coords, exactly like the reference
    const float wx1 = (float)x1c - x;   // multiplies x0c column
    const float wx0 = x - (float)x0c;   // multiplies x1c column
    const float wy1 = (float)y1c - y;   // multiplies y0c row
    const float wy0 = y - (float)y0c;   // multiplies y1c row

    const float wa = wx1 * wy1;  // (y0c, x0c)
    const float wb = wx1 * wy0;  // (y1c, x0c)
    const float wc = wx0 * wy1;  // (y0c, x1c)
    const float wd = wx0 * wy0;  // (y1c, x1c)

    const int b = pix >> 16;  // H*W = 65536
    const size_t imgbase = (size_t)b * (size_t)(Hn * Wn * Cn);

    const float4* pa = (const float4*)(img + imgbase + ((size_t)(y0c * Wn + x0c)) * Cn) + cg;
    const float4* pb = (const float4*)(img + imgbase + ((size_t)(y1c * Wn + x0c)) * Cn) + cg;
    const float4* pc = (const float4*)(img + imgbase + ((size_t)(y0c * Wn + x1c)) * Cn) + cg;
    const float4* pd = (const float4*)(img + imgbase + ((size_t)(y1c * Wn + x1c)) * Cn) + cg;

    const float4 va = *pa;
    const float4 vb = *pb;
    const float4 vc = *pc;
    const float4 vd = *pd;

    float4 o;
    o.x = wa * va.x + wb * vb.x + wc * vc.x + wd * vd.x;
    o.y = wa * va.y + wb * vb.y + wc * vc.y + wd * vd.y;
    o.z = wa * va.z + wb * vb.z + wc * vc.z + wd * vd.z;
    o.w = wa * va.w + wb * vb.w + wc * vc.w + wd * vd.w;

    ((float4*)out)[(size_t)pix * CG + cg] = o;
}

extern "C" void kernel_launch(void* const* d_in, const int* in_sizes, int n_in,
                              void* d_out, int out_size, void* d_ws, size_t ws_size,
                              hipStream_t stream)
{
    const float* img = (const float*)d_in[0];
    const float* xs  = (const float*)d_in[1];
    const float* ys  = (const float*)d_in[2];
    float* out       = (float*)d_out;

    const int total_threads = Bn * Hn * Wn * CG;  // 8,388,608
    const int block = 256;
    const int grid  = total_threads / block;      // 32768

    bilinear_kernel<<<grid, block, 0, stream>>>(img, xs, ys, out);
}

// Round 2
// 253.638 us; speedup vs baseline: 1.0043x; 1.0043x over previous
//
#include <hip/hip_runtime.h>

// BilinearSampler: img [B,H,W,C] f32, x_s/y_s [B,H,W] f32 in [-1,1] -> out [B,H,W,C] f32
// B=16, H=256, W=256, C=32.
// Mapping: 8 threads per pixel, each thread handles one float4 channel group.
// Wave of 64 lanes = 8 consecutive pixels * full C -> 1 KiB contiguous store.
// R2: non-temporal output stores + coord loads so the 134 MB write stream and
//     8 MB coord stream don't evict the (L3-resident) image; image corner
//     re-reads then hit Infinity Cache instead of HBM.

constexpr int Bn = 16;
constexpr int Hn = 256;
constexpr int Wn = 256;
constexpr int Cn = 32;
constexpr int CG = Cn / 4;  // 8 float4 groups per pixel

typedef float f4 __attribute__((ext_vector_type(4)));

__global__ __launch_bounds__(256) void bilinear_kernel(
    const float* __restrict__ img,
    const float* __restrict__ xs,
    const float* __restrict__ ys,
    float* __restrict__ out)
{
    const int t   = blockIdx.x * blockDim.x + threadIdx.x;
    const int pix = t >> 3;        // pixel index over B*H*W (grid sized exactly)
    const int cg  = t & 7;         // channel group (float4 index)

    const float xsv = __builtin_nontemporal_load(xs + pix);
    const float ysv = __builtin_nontemporal_load(ys + pix);

    const float x = 0.5f * (xsv + 1.0f) * (float)(Wn - 1);
    const float y = 0.5f * (ysv + 1.0f) * (float)(Hn - 1);

    const float xf = floorf(x);
    const float yf = floorf(y);
    int x0 = (int)xf;
    int y0 = (int)yf;
    int x1 = x0 + 1;
    int y1 = y0 + 1;

    const int x0c = min(max(x0, 0), Wn - 1);
    const int x1c = min(max(x1, 0), Wn - 1);
    const int y0c = min(max(y0, 0), Hn - 1);
    const int y1c = min(max(y1, 0), Hn - 1);

    // weights from CLAMPED coords, exactly like the reference
    const float wx1 = (float)x1c - x;   // multiplies x0c column
    const float wx0 = x - (float)x0c;   // multiplies x1c column
    const float wy1 = (float)y1c - y;   // multiplies y0c row
    const float wy0 = y - (float)y0c;   // multiplies y1c row

    const float wa = wx1 * wy1;  // (y0c, x0c)
    const float wb = wx1 * wy0;  // (y1c, x0c)
    const float wc = wx0 * wy1;  // (y0c, x1c)
    const float wd = wx0 * wy0;  // (y1c, x1c)

    const int b = pix >> 16;  // H*W = 65536
    const size_t imgbase = (size_t)b * (size_t)(Hn * Wn * Cn);

    const f4* pa = (const f4*)(img + imgbase + ((size_t)(y0c * Wn + x0c)) * Cn) + cg;
    const f4* pb = (const f4*)(img + imgbase + ((size_t)(y1c * Wn + x0c)) * Cn) + cg;
    const f4* pc = (const f4*)(img + imgbase + ((size_t)(y0c * Wn + x1c)) * Cn) + cg;
    const f4* pd = (const f4*)(img + imgbase + ((size_t)(y1c * Wn + x1c)) * Cn) + cg;

    const f4 va = *pa;
    const f4 vb = *pb;
    const f4 vc = *pc;
    const f4 vd = *pd;

    f4 o;
    o.x = wa * va.x + wb * vb.x + wc * vc.x + wd * vd.x;
    o.y = wa * va.y + wb * vb.y + wc * vc.y + wd * vd.y;
    o.z = wa * va.z + wb * vb.z + wc * vc.z + wd * vd.z;
    o.w = wa * va.w + wb * vb.w + wc * vc.w + wd * vd.w;

    f4* op = (f4*)out + (size_t)pix * CG + cg;
    __builtin_nontemporal_store(o, op);
}

extern "C" void kernel_launch(void* const* d_in, const int* in_sizes, int n_in,
                              void* d_out, int out_size, void* d_ws, size_t ws_size,
                              hipStream_t stream)
{
    const float* img = (const float*)d_in[0];
    const float* xs  = (const float*)d_in[1];
    const float* ys  = (const float*)d_in[2];
    float* out       = (float*)d_out;

    const int total_threads = Bn * Hn * Wn * CG;  // 8,388,608
    const int block = 256;
    const int grid  = total_threads / block;      // 32768

    bilinear_kernel<<<grid, block, 0, stream>>>(img, xs, ys, out);
}

// Round 3
// 250.007 us; speedup vs baseline: 1.0189x; 1.0145x over previous
//
#include <hip/hip_runtime.h>

// BilinearSampler: img [B,H,W,C] f32, x_s/y_s [B,H,W] f32 in [-1,1] -> out [B,H,W,C] f32
// B=16, H=256, W=256, C=32.
// Mapping: 8 threads per pixel, each thread handles one float4 channel group.
// Wave of 64 lanes = 8 consecutive pixels * full C -> coalesced 1 KiB store.
// R3: 4 pixel-groups per thread, software-pipelined — all coord loads issued
//     first, then all 16 gather loads, then consume. 4x memory-level
//     parallelism per wave to cover gather latency (R2 showed 3.8 TB/s at
//     VALUBusy 15% => latency-bound, not BW-bound).

constexpr int Bn = 16;
constexpr int Hn = 256;
constexpr int Wn = 256;
constexpr int Cn = 32;
constexpr int CG = Cn / 4;   // 8 float4 groups per pixel
constexpr int NP = 4;        // pixel-groups per thread

typedef float f4 __attribute__((ext_vector_type(4)));

__global__ __launch_bounds__(256) void bilinear_kernel(
    const float* __restrict__ img,
    const float* __restrict__ xs,
    const float* __restrict__ ys,
    float* __restrict__ out)
{
    const int tid = threadIdx.x;
    const int cg  = tid & 7;          // channel group (float4 index)
    const int lp  = tid >> 3;         // local pixel 0..31
    // block covers 128 consecutive pixels as 4 chunks of 32
    const int base_pix = blockIdx.x * 128 + lp;

    int pix[NP];
    float xsv[NP], ysv[NP];
#pragma unroll
    for (int g = 0; g < NP; ++g) {
        pix[g] = base_pix + g * 32;
        xsv[g] = __builtin_nontemporal_load(xs + pix[g]);
        ysv[g] = __builtin_nontemporal_load(ys + pix[g]);
    }

    float wa[NP], wb[NP], wc[NP], wd[NP];
    const f4* pa[NP];
    const f4* pb[NP];
    const f4* pc[NP];
    const f4* pd[NP];

#pragma unroll
    for (int g = 0; g < NP; ++g) {
        const float x = 0.5f * (xsv[g] + 1.0f) * (float)(Wn - 1);
        const float y = 0.5f * (ysv[g] + 1.0f) * (float)(Hn - 1);

        const int x0 = (int)floorf(x);
        const int y0 = (int)floorf(y);

        const int x0c = min(max(x0, 0), Wn - 1);
        const int x1c = min(max(x0 + 1, 0), Wn - 1);
        const int y0c = min(max(y0, 0), Hn - 1);
        const int y1c = min(max(y0 + 1, 0), Hn - 1);

        const float wx1 = (float)x1c - x;
        const float wx0 = x - (float)x0c;
        const float wy1 = (float)y1c - y;
        const float wy0 = y - (float)y0c;

        wa[g] = wx1 * wy1;
        wb[g] = wx1 * wy0;
        wc[g] = wx0 * wy1;
        wd[g] = wx0 * wy0;

        const int b = pix[g] >> 16;  // H*W = 65536
        const size_t imgbase = (size_t)b * (size_t)(Hn * Wn * Cn);

        pa[g] = (const f4*)(img + imgbase + ((size_t)(y0c * Wn + x0c)) * Cn) + cg;
        pb[g] = (const f4*)(img + imgbase + ((size_t)(y1c * Wn + x0c)) * Cn) + cg;
        pc[g] = (const f4*)(img + imgbase + ((size_t)(y0c * Wn + x1c)) * Cn) + cg;
        pd[g] = (const f4*)(img + imgbase + ((size_t)(y1c * Wn + x1c)) * Cn) + cg;
    }

    // issue all 16 gather loads before consuming any
    f4 va[NP], vb[NP], vc[NP], vd[NP];
#pragma unroll
    for (int g = 0; g < NP; ++g) {
        va[g] = *pa[g];
        vb[g] = *pb[g];
        vc[g] = *pc[g];
        vd[g] = *pd[g];
    }

#pragma unroll
    for (int g = 0; g < NP; ++g) {
        f4 o;
        o.x = wa[g] * va[g].x + wb[g] * vb[g].x + wc[g] * vc[g].x + wd[g] * vd[g].x;
        o.y = wa[g] * va[g].y + wb[g] * vb[g].y + wc[g] * vc[g].y + wd[g] * vd[g].y;
        o.z = wa[g] * va[g].z + wb[g] * vb[g].z + wc[g] * vc[g].z + wd[g] * vd[g].z;
        o.w = wa[g] * va[g].w + wb[g] * vb[g].w + wc[g] * vc[g].w + wd[g] * vd[g].w;

        f4* op = (f4*)out + (size_t)pix[g] * CG + cg;
        __builtin_nontemporal_store(o, op);
    }
}

extern "C" void kernel_launch(void* const* d_in, const int* in_sizes, int n_in,
                              void* d_out, int out_size, void* d_ws, size_t ws_size,
                              hipStream_t stream)
{
    const float* img = (const float*)d_in[0];
    const float* xs  = (const float*)d_in[1];
    const float* ys  = (const float*)d_in[2];
    float* out       = (float*)d_out;

    const int total_pixels = Bn * Hn * Wn;        // 1,048,576
    const int block = 256;
    const int grid  = total_pixels / 128;         // 8192 blocks, 128 px/block

    bilinear_kernel<<<grid, block, 0, stream>>>(img, xs, ys, out);
}